// Round 4
// baseline (421.656 us; speedup 1.0000x reference)
//
#include <hip/hip_runtime.h>
#include <hip/hip_bf16.h>
#include <math.h>

typedef unsigned short u16;
typedef __attribute__((ext_vector_type(8))) short short8;
typedef __attribute__((ext_vector_type(4))) float floatx4;

__device__ __forceinline__ float lk(float v){ return v >= 0.f ? v : 0.01f*v; }
__device__ __forceinline__ u16 f2b(float f){
    __hip_bfloat16 h = __float2bfloat16(f);
    return *reinterpret_cast<u16*>(&h);
}
__device__ __forceinline__ int refl(int t, int L){
    return t < 0 ? -t : (t >= L ? 2*L-2-t : t);
}

// ---------------------------------------------------------------------------
// Weight pre-conversion (unchanged layout):
//   [0,4096)        wb1  hconv1: (((s*4+kq)*32)+o)*8+j
//   [4096,18432)    wb2  hconv2: (((s*4+kq)*64)+o)*8+j
//   [18432,75776)   wbe  econv2: (((s*4+kq)*128)+o)*8+j
//   [75776,92160)   gwb  gconv:  (((gi*2+tb)*64)+o)*8+j
// ---------------------------------------------------------------------------
__global__ __launch_bounds__(256) void k_prep(const float* __restrict__ hw1,
        const float* __restrict__ hw2, const float* __restrict__ ew2,
        const float* __restrict__ gw, u16* __restrict__ wb)
{
    int idx = blockIdx.x*256 + threadIdx.x;
    if (idx < 4096){
        int u = idx; int j=u&7; int o=(u>>3)&31; int kq=(u>>8)&3; int s=u>>10;
        int tap = 2*s + (kq>>1); int ic = (kq&1)*8 + j;
        wb[idx] = (tap<7) ? f2b(hw1[(o*16+ic)*7+tap]) : (u16)0;
    } else if (idx < 18432){
        int u = idx - 4096; int j=u&7; int o=(u>>3)&63; int kq=(u>>9)&3; int s=u>>11;
        wb[idx] = f2b(hw2[(o*32 + kq*8 + j)*7 + s]);
    } else if (idx < 75776){
        int u = idx - 18432; int j=u&7; int o=(u>>3)&127; int kq=(u>>10)&3; int s=u>>12;
        int ih = s/7, tap = s-ih*7;
        wb[idx] = f2b(ew2[(o*64 + ih*32 + kq*8 + j)*7 + tap]);
    } else if (idx < 92160){
        int u = idx - 75776; int j=u&7; int o=(u>>3)&63; int tb=(u>>9)&1; int gi=u>>10;
        int tap = tb*8 + j;
        wb[idx] = (tap<15) ? f2b(gw[gi*960 + o*15 + tap]) : (u16)0;
    }
}

// ---------------------------------------------------------------------------
// Hypernet conv1 v5: persistent blocks, 6 tiles of 256 pos each, rolling
// dbuf pipeline; each wave owns a 64-pos quarter and computes BOTH o-halves
// per ds_read (halved LDS read traffic).  grid 1024 = 4 blocks/CU.
// ---------------------------------------------------------------------------
__global__ __launch_bounds__(256,4) void k_hconv1(const float* __restrict__ x,
        const u16* __restrict__ wb1, const float* __restrict__ bias,
        u16* __restrict__ h1)
{
    __shared__ __align__(16) u16 xs[2][264*24];
    __shared__ __align__(16) u16 ob[2][64*32];
    int b = blockIdx.x >> 3, chunk = blockIdx.x & 7;   // 8 chunks x 6 tiles
    int tid = threadIdx.x;
    const float* xb = x + (size_t)b*16*12288;
    int wv = tid >> 6, lane = tid & 63;
    int m = lane & 15, kq = lane >> 4;
    int tq = wv;                                  // wave owns 64-pos quarter

    short8 wfr[4][2];
    #pragma unroll
    for (int s=0;s<4;s++)
        #pragma unroll
        for (int oh=0;oh<2;oh++)
            wfr[s][oh] = *reinterpret_cast<const short8*>(
                            &wb1[(((s*4+kq)*32) + oh*16 + m)*8]);
    float bv[2] = { bias[m], bias[16+m] };

    float rg0[16]; float rgx;
    int exrow = 256 + (tid>>4), exch = tid & 15;

#define LOADTILE(G0) { \
        int t0 = refl((G0) - 3 + tid, 12288); \
        _Pragma("unroll") \
        for (int ic=0;ic<16;ic++) rg0[ic] = xb[(size_t)ic*12288 + t0]; \
        if (tid < 128){ \
            int t1 = refl((G0) - 3 + exrow, 12288); \
            rgx = xb[(size_t)exch*12288 + t1]; \
        } \
        __builtin_amdgcn_sched_barrier(0); }

#define WRITETILE(BUF) { \
        short8 p0, p1; \
        _Pragma("unroll") \
        for (int j=0;j<8;j++){ p0[j] = (short)f2b(rg0[j]); p1[j] = (short)f2b(rg0[8+j]); } \
        *reinterpret_cast<short8*>(&xs[BUF][tid*24])     = p0; \
        *reinterpret_cast<short8*>(&xs[BUF][tid*24 + 8]) = p1; \
        if (tid < 128) xs[BUF][exrow*24 + exch] = f2b(rgx); }

#define COMPUTETILE(BUF) { \
        floatx4 acc[4][2]; \
        _Pragma("unroll") \
        for (int i=0;i<4;i++){ acc[i][0] = (floatx4){0.f,0.f,0.f,0.f}; \
                               acc[i][1] = (floatx4){0.f,0.f,0.f,0.f}; } \
        _Pragma("unroll") \
        for (int sub=0; sub<4; sub++){ \
            int tb = tq*64 + sub*16; \
            _Pragma("unroll") \
            for (int s=0;s<4;s++){ \
                int tap = 2*s + (kq>>1); \
                short8 xfr = *reinterpret_cast<const short8*>( \
                                &xs[BUF][(tb + m + tap)*24 + (kq&1)*8]); \
                acc[sub][0] = __builtin_amdgcn_mfma_f32_16x16x32_bf16(xfr, wfr[s][0], acc[sub][0], 0,0,0); \
                acc[sub][1] = __builtin_amdgcn_mfma_f32_16x16x32_bf16(xfr, wfr[s][1], acc[sub][1], 0,0,0); \
            } \
        } \
        _Pragma("unroll") \
        for (int sub=0; sub<4; sub++){ \
            int p = tq*16 + sub*4 + kq; \
            _Pragma("unroll") \
            for (int oh=0; oh<2; oh++){ \
                float sum = lk(acc[sub][oh][0]+bv[oh]) + lk(acc[sub][oh][1]+bv[oh]) \
                          + lk(acc[sub][oh][2]+bv[oh]) + lk(acc[sub][oh][3]+bv[oh]); \
                ob[BUF][p*32 + oh*16 + m] = f2b(sum*0.25f); \
            } \
        } }

#define STORETILE(BUF, TAU) { \
        short8 v = *reinterpret_cast<const short8*>(&ob[BUF][tid*8]); \
        *reinterpret_cast<short8*>(&h1[((size_t)b*3072 + (TAU)*64)*32 + tid*8]) = v; }

    int tau0 = chunk*6;
    LOADTILE(tau0*256);
    WRITETILE(0);
    __syncthreads();
    LOADTILE((tau0+1)*256);
    #pragma unroll 1
    for (int t=0; t<6; ++t){
        int cur = t & 1;
        COMPUTETILE(cur);
        if (t < 5) WRITETILE(cur^1);
        __syncthreads();
        STORETILE(cur, tau0 + t);
        if (t < 4) LOADTILE((tau0 + t + 2)*256);
    }

#undef LOADTILE
#undef WRITETILE
#undef COMPUTETILE
#undef STORETILE
}

// ---------------------------------------------------------------------------
// Hypernet conv2 v4: h1 bf16 [b][3072][32] -> h2 f32 [b][768 pos][64 ch].
// Waves partition M (3 subtiles each) and compute all 64 oc in 2 n-chunks:
// one ds_read feeds 2 MFMAs -> LDS read traffic halved.
// ---------------------------------------------------------------------------
__global__ __launch_bounds__(256,3) void k_hconv2(const u16* __restrict__ h1,
        const u16* __restrict__ wb2, const float* __restrict__ bias,
        float* __restrict__ h2)
{
    __shared__ __align__(16) u16 xs[2][198*40];
    int b = blockIdx.x >> 3, tile = blockIdx.x & 7;
    int tid = threadIdx.x;
    int wv = tid >> 6, lane = tid & 63;
    int m = lane & 15, kq = lane >> 4;

    float bv[4];
    #pragma unroll
    for (int nt=0;nt<4;nt++) bv[nt] = bias[nt*16 + m];

    short8 rgA[3], rgX;

#define LOADH(HALF) { \
        int gh = tile*384 + (HALF)*192 - 3; \
        _Pragma("unroll") \
        for (int cc=0;cc<3;cc++){ \
            int c = tid + cc*256; \
            int row = c >> 2, q = c & 3; \
            int t = refl(gh + row, 3072); \
            rgA[cc] = *reinterpret_cast<const short8*>(&h1[((size_t)b*3072 + t)*32 + q*8]); \
        } \
        if (tid < 24){ \
            int c = 768 + tid; \
            int row = c >> 2, q = c & 3; \
            int t = refl(gh + row, 3072); \
            rgX = *reinterpret_cast<const short8*>(&h1[((size_t)b*3072 + t)*32 + q*8]); \
        } \
        __builtin_amdgcn_sched_barrier(0); }

#define WRITEH(BUF) { \
        _Pragma("unroll") \
        for (int cc=0;cc<3;cc++){ \
            int c = tid + cc*256; \
            *reinterpret_cast<short8*>(&xs[BUF][(c>>2)*40 + (c&3)*8]) = rgA[cc]; \
        } \
        if (tid < 24){ \
            int c = 768 + tid; \
            *reinterpret_cast<short8*>(&xs[BUF][(c>>2)*40 + (c&3)*8]) = rgX; \
        } }

#define COMPUTEH(BUF, HALF) { \
        floatx4 acc[3][4]; \
        _Pragma("unroll") \
        for (int i=0;i<3;i++) \
            _Pragma("unroll") \
            for (int nt=0;nt<4;nt++) acc[i][nt] = (floatx4){0.f,0.f,0.f,0.f}; \
        _Pragma("unroll") \
        for (int nt2=0; nt2<2; ++nt2){ \
            short8 wfr[7][2]; \
            _Pragma("unroll") \
            for (int s=0;s<7;s++) \
                _Pragma("unroll") \
                for (int c=0;c<2;c++) \
                    wfr[s][c] = *reinterpret_cast<const short8*>( \
                        &wb2[(((s*4+kq)*64) + (nt2*2+c)*16 + m)*8]); \
            _Pragma("unroll") \
            for (int i=0;i<3;i++){ \
                int tb = (wv*3+i)*16; \
                _Pragma("unroll") \
                for (int s=0;s<7;s++){ \
                    short8 xfr = *reinterpret_cast<const short8*>( \
                                    &xs[BUF][(tb + m + s)*40 + kq*8]); \
                    acc[i][nt2*2]   = __builtin_amdgcn_mfma_f32_16x16x32_bf16(xfr, wfr[s][0], acc[i][nt2*2],   0,0,0); \
                    acc[i][nt2*2+1] = __builtin_amdgcn_mfma_f32_16x16x32_bf16(xfr, wfr[s][1], acc[i][nt2*2+1], 0,0,0); \
                } \
            } \
        } \
        _Pragma("unroll") \
        for (int i=0;i<3;i++){ \
            int pooled = (wv*3+i)*4 + kq; \
            _Pragma("unroll") \
            for (int nt=0;nt<4;nt++){ \
                float sum = lk(acc[i][nt][0]+bv[nt]) + lk(acc[i][nt][1]+bv[nt]) \
                          + lk(acc[i][nt][2]+bv[nt]) + lk(acc[i][nt][3]+bv[nt]); \
                h2[((size_t)b*768 + tile*96 + (HALF)*48 + pooled)*64 + nt*16 + m] = sum*0.25f; \
            } \
        } }

    LOADH(0);
    WRITEH(0);
    __syncthreads();
    LOADH(1);
    COMPUTEH(0, 0);
    WRITEH(1);
    __syncthreads();
    COMPUTEH(1, 1);

#undef LOADH
#undef WRITEH
#undef COMPUTEH
}

// ---------------------------------------------------------------------------
// Hypernet conv3 FUSED: h2 f32 [b][768][64] -> latent[128,6144]. (unchanged)
// ---------------------------------------------------------------------------
__global__ __launch_bounds__(256) void k_hconv3(const float* __restrict__ h2,
        const float* __restrict__ w, const float* __restrict__ bias,
        float* __restrict__ latent)
{
    __shared__ float xs[64*201];
    int b = blockIdx.x >> 2, tile = blockIdx.x & 3;
    int g0 = tile*192;
    int tid = threadIdx.x;
    for (int idx = tid; idx < 198*64; idx += 256){
        int jj = idx >> 6, ic = idx & 63;
        int t = refl(g0 + jj - 3, 768);
        xs[ic*201 + jj] = h2[((size_t)b*768 + t)*64 + ic];
    }
    __syncthreads();
    int c = tid >> 5, run = tid & 31;
    int p0 = run*6;
    float acc[6];
    #pragma unroll
    for (int l=0;l<6;l++) acc[l] = 0.f;
    for (int ic=0; ic<64; ic++){
        const float* wp = w + (c*64+ic)*7;
        float wr[7];
        #pragma unroll
        for (int s=0;s<7;s++) wr[s] = wp[s];
        const float* xr = xs + ic*201 + p0;
        float xw[12];
        #pragma unroll
        for (int j=0;j<12;j++) xw[j] = xr[j];
        #pragma unroll
        for (int s=0;s<7;s++)
            #pragma unroll
            for (int l=0;l<6;l++) acc[l] += wr[s]*xw[l+s];
    }
    float bv = bias[c];
    float* op = latent + (size_t)b*6144 + c*768 + g0 + p0;
    #pragma unroll
    for (int l=0;l<6;l++) op[l] = tanhf(acc[l] + bv);
}

// ---------------------------------------------------------------------------
// t1 = leaky(latent @ hl1^T).  (unchanged)
// ---------------------------------------------------------------------------
__global__ __launch_bounds__(256) void k_lin1(const float* __restrict__ latent,
        const float* __restrict__ hl1, float* __restrict__ t1)
{
    __shared__ float ls[6144];
    int b = blockIdx.x / 6, ntile = blockIdx.x % 6;
    int tid = threadIdx.x;
    const float4* lp = reinterpret_cast<const float4*>(latent + (size_t)b*6144);
    float4* lsv = reinterpret_cast<float4*>(ls);
    for (int i = tid; i < 1536; i += 256) lsv[i] = lp[i];
    __syncthreads();
    int wv = tid >> 6, lane = tid & 63;
    #pragma unroll
    for (int nn=0; nn<4; nn++){
        int n = ntile*16 + wv*4 + nn;
        const float4* wp = reinterpret_cast<const float4*>(hl1 + (size_t)n*6144);
        float s = 0.f;
        #pragma unroll
        for (int j=0;j<24;j++){
            float4 q = wp[lane + 64*j];
            float4 l4 = lsv[lane + 64*j];
            s += l4.x*q.x + l4.y*q.y + l4.z*q.z + l4.w*q.w;
        }
        #pragma unroll
        for (int off=32; off; off>>=1) s += __shfl_down(s, off);
        if (lane==0) t1[b*96+n] = lk(s);
    }
}

// ---------------------------------------------------------------------------
// logits = t1 @ hl2^T; top-5; n0 = #(idx<6)   (unchanged)
// ---------------------------------------------------------------------------
__global__ __launch_bounds__(128) void k_topk(const float* __restrict__ t1,
        const float* __restrict__ hl2, int* __restrict__ idxb, float* __restrict__ n0f)
{
    __shared__ float lg[96];
    int b = blockIdx.x, n = threadIdx.x;
    if (n < 96){
        float s = 0.f;
        const float* tp = t1 + b*96;
        const float* wp = hl2 + n*96;
        for (int m=0;m<96;m++) s += tp[m]*wp[m];
        lg[n] = s;
    }
    __syncthreads();
    if (threadIdx.x == 0){
        unsigned long long u0=0ull, u1=0ull;
        float n0 = 0.f;
        for (int k=0;k<5;k++){
            float best = -3.4e38f; int bi = 0;
            for (int m=0;m<96;m++){
                bool used = m<64 ? ((u0>>m)&1ull) : ((u1>>(m-64))&1ull);
                if (!used && lg[m] > best){ best = lg[m]; bi = m; }
            }
            if (bi<64) u0 |= 1ull<<bi; else u1 |= 1ull<<(bi-64);
            idxb[b*5+k] = bi;
            if (bi < 6) n0 += 1.f;
        }
        n0f[b] = n0;
    }
}

// ---------------------------------------------------------------------------
// Grouped idx conv (MFMA), weights from pre-baked gwb. (unchanged)
// ---------------------------------------------------------------------------
__global__ __launch_bounds__(256,3) void k_gconv(const float* __restrict__ x,
        const int* __restrict__ idxb, const float* __restrict__ n0f,
        const u16* __restrict__ gwb, const float* __restrict__ gb0,
        u16* __restrict__ zp)
{
    __shared__ __align__(16) u16 xs[5][8][536];
    __shared__ int nidx[5];
    __shared__ float n0s;
    int b = blockIdx.x >> 2, qc = blockIdx.x & 3;
    int tid = threadIdx.x;
    int p0g = qc*512;

    if (tid < 5) nidx[tid] = idxb[b*5 + tid];
    if (tid == 5) n0s = n0f[b];
    __syncthreads();

    for (int cch = tid; cch < 5*134; cch += 256){
        int k = cch / 134, q = cch - k*134;
        const float* xrow = x + (size_t)b*196608 + (size_t)nidx[k]*2048;
        int base = p0g + q*4;
        u16 vb[4];
        if (base + 3 <= 2047){
            float4 a = *reinterpret_cast<const float4*>(xrow + base);
            vb[0]=f2b(a.x); vb[1]=f2b(a.y); vb[2]=f2b(a.z); vb[3]=f2b(a.w);
        } else {
            #pragma unroll
            for (int jj=0;jj<4;jj++){
                int ii = base+jj; if (ii > 2047) ii = 2047;
                vb[jj] = f2b(xrow[ii]);
            }
        }
        #pragma unroll
        for (int jj=0;jj<4;jj++){
            int gof = q*4 + jj;
            #pragma unroll
            for (int r=0;r<8;r++){
                int i = gof - r;
                if (i >= 0 && i < 528) xs[k][r][i] = vb[jj];
            }
        }
    }

    int wv = tid >> 6, lane = tid & 63;
    int m = lane & 15, kq = lane >> 4;
    int o = wv*16 + m;

    short8 wfr[3];
    #pragma unroll
    for (int c=0;c<3;c++){
        int kk = 2*c + (kq>>1);
        int kkc = kk < 5 ? kk : 4;
        int gi = nidx[kkc] / 6;
        short8 f = *reinterpret_cast<const short8*>(
                        &gwb[(((gi*2 + (kq&1))*64)+o)*8]);
        if (kk >= 5) f = (short8)(short)0;
        wfr[c] = f;
    }
    float bv = n0s * gb0[o];
    __syncthreads();

    int rr = m & 7, ibase = (m & 8) + (kq & 1)*8;
    for (int g8 = 0; g8 < 4; ++g8){
        floatx4 acc[8];
        #pragma unroll
        for (int i=0;i<8;i++) acc[i] = (floatx4){0.f,0.f,0.f,0.f};
        #pragma unroll
        for (int s8=0; s8<8; ++s8){
            int P = (g8*8 + s8)*16;
            #pragma unroll
            for (int c=0;c<3;c++){
                int kk = 2*c + (kq>>1);
                int kkc = kk < 5 ? kk : 4;
                short8 af = *reinterpret_cast<const short8*>(&xs[kkc][rr][P + ibase]);
                acc[s8] = __builtin_amdgcn_mfma_f32_16x16x32_bf16(af, wfr[c], acc[s8], 0,0,0);
            }
        }
        #pragma unroll
        for (int s8=0; s8<8; ++s8){
            int sub = g8*8 + s8;
            int Q = qc*128 + sub*4 + kq;
            if (Q < 508){
                float mx = fmaxf(fmaxf(lk(acc[s8][0]+bv), lk(acc[s8][1]+bv)),
                                 fmaxf(lk(acc[s8][2]+bv), lk(acc[s8][3]+bv)));
                zp[((size_t)b*508 + Q)*64 + o] = f2b(mx);
            }
        }
    }
}

// ---------------------------------------------------------------------------
// Encoder conv2 (MFMA): zp bf16 [b][508][64] -> p2 f32 [b][125][128].
// Now (256,2) for 2 resident blocks/CU.
// ---------------------------------------------------------------------------
__global__ __launch_bounds__(256,2) void k_econv2(const u16* __restrict__ zp,
        const u16* __restrict__ wbe, const float* __restrict__ bias,
        float* __restrict__ p2)
{
    __shared__ __align__(16) u16 xs[118*72];
    int b = blockIdx.x / 5, tile = blockIdx.x % 5;
    int tid = threadIdx.x;
    for (int c = tid; c < 118*8; c += 256){
        int row = c >> 3, q = c & 7;
        int t = tile*100 + row; if (t > 507) t = 507;
        *reinterpret_cast<short8*>(&xs[row*72 + q*8]) =
            *reinterpret_cast<const short8*>(&zp[((size_t)b*508 + t)*64 + q*8]);
    }
    __syncthreads();
    int wv = tid >> 6, lane = tid & 63;
    int m = lane & 15, kq = lane >> 4;
    for (int half=0; half<2; half++){
        int ot = wv + 4*half;
        int o = ot*16 + m;
        short8 wfr[14];
        #pragma unroll
        for (int s=0;s<14;s++)
            wfr[s] = *reinterpret_cast<const short8*>(&wbe[(((s*4+kq)*128)+o)*8]);
        floatx4 acc[7];
        #pragma unroll
        for (int i=0;i<7;i++) acc[i] = (floatx4){0.f,0.f,0.f,0.f};
        #pragma unroll
        for (int sub=0; sub<7; sub++){
            #pragma unroll
            for (int s=0;s<14;s++){
                int tap = s%7, ih = s/7;
                short8 xfr = *reinterpret_cast<const short8*>(
                                &xs[(sub*16 + m + tap)*72 + ih*32 + kq*8]);
                acc[sub] = __builtin_amdgcn_mfma_f32_16x16x32_bf16(xfr, wfr[s], acc[sub], 0,0,0);
            }
        }
        float bv = bias[o];
        #pragma unroll
        for (int sub=0; sub<7; sub++){
            int pidx = sub*4 + kq;
            if (pidx < 25){
                float mx = fmaxf(fmaxf(lk(acc[sub][0]+bv), lk(acc[sub][1]+bv)),
                                 fmaxf(lk(acc[sub][2]+bv), lk(acc[sub][3]+bv)));
                p2[((size_t)b*125 + tile*25 + pidx)*128 + o] = mx;
            }
        }
    }
}

// ---------------------------------------------------------------------------
// Fused tail: sliding sums + feat + classifier + log_softmax. (unchanged)
// ---------------------------------------------------------------------------
__global__ __launch_bounds__(128) void k_tail(const float* __restrict__ p2,
        const float* __restrict__ w, const float* __restrict__ bias,
        const float* __restrict__ cw, const float* __restrict__ cb,
        float* __restrict__ out)
{
    __shared__ float ss[7][128];
    __shared__ float ft[128];
    __shared__ float lgs[5];
    int b = blockIdx.x, tid = threadIdx.x;

    {
        const float* pb = p2 + (size_t)b*125*128 + tid;
        float first6[6], last6[6];
        float c = 0.f;
        #pragma unroll
        for (int t=0;t<6;t++){ float v = pb[(size_t)t*128]; first6[t]=v; c+=v; }
        for (int t=6;t<119;t++) c += pb[(size_t)t*128];
        #pragma unroll
        for (int t=0;t<6;t++) last6[t] = pb[(size_t)(119+t)*128];
        ss[0][tid] = c;
        #pragma unroll
        for (int s=0;s<6;s++){ c = c - first6[s] + last6[s]; ss[s+1][tid] = c; }
    }
    __syncthreads();

    {
        const float* wp = w + (size_t)tid*896;
        float s = 0.f;
        for (int ic=0; ic<128; ic++){
            #pragma unroll
            for (int tp=0; tp<7; tp++)
                s += wp[ic*7+tp]*ss[tp][ic];
        }
        ft[tid] = s*(1.f/119.f) + bias[tid];
    }
    __syncthreads();

    if (tid < 5){
        float lg = cb[tid];
        const float* wp = cw + tid*128;
        for (int o=0;o<128;o++) lg += ft[o]*wp[o];
        lgs[tid] = lg;
    }
    __syncthreads();
    if (tid == 0){
        float mx = -3.4e38f;
        for (int c=0;c<5;c++) mx = fmaxf(mx, lgs[c]);
        float se = 0.f;
        for (int c=0;c<5;c++) se += expf(lgs[c]-mx);
        float lse = mx + logf(se);
        for (int c=0;c<5;c++) out[b*5+c] = lgs[c]-lse;
    }
}

extern "C" void kernel_launch(void* const* d_in, const int* in_sizes, int n_in,
                              void* d_out, int out_size, void* d_ws, size_t ws_size,
                              hipStream_t stream)
{
    const float* x   = (const float*)d_in[0];
    const float* hw1 = (const float*)d_in[2];
    const float* hb1 = (const float*)d_in[3];
    const float* hw2 = (const float*)d_in[4];
    const float* hb2 = (const float*)d_in[5];
    const float* hw3 = (const float*)d_in[6];
    const float* hb3 = (const float*)d_in[7];
    const float* hl1 = (const float*)d_in[8];
    const float* hl2 = (const float*)d_in[9];
    const float* gw  = (const float*)d_in[10];
    const float* gb0 = (const float*)d_in[11];
    const float* ew2 = (const float*)d_in[12];
    const float* eb2 = (const float*)d_in[13];
    const float* ew3 = (const float*)d_in[14];
    const float* eb3 = (const float*)d_in[15];
    const float* cw  = (const float*)d_in[16];
    const float* cb  = (const float*)d_in[17];
    float* out = (float*)d_out;

    float* f       = (float*)d_ws;
    float* latent  = f;                       // [0, 786432)
    float* t1      = f + 786432;
    int*   idxb    = (int*)(f + 806432);
    float* n0f     = f + 808432;
    u16*   zpb     = (u16*)(f + 810000);
    u16*   wb      = (u16*)(f + 2900000);
    float* h2      = f + 3932160;
    float* p2      = f + 5000000;
    u16*   h1b     = (u16*)(f + 10223616);

    k_prep<<<360, 256, 0, stream>>>(hw1, hw2, ew2, gw, wb);
    k_hconv1<<<1024, 256, 0, stream>>>(x, wb, hb1, h1b);
    k_hconv2<<<1024, 256, 0, stream>>>(h1b, wb + 4096, hb2, h2);
    k_hconv3<<<512, 256, 0, stream>>>(h2, hw3, hb3, latent);
    k_lin1<<<768, 256, 0, stream>>>(latent, hl1, t1);
    k_topk<<<128, 128, 0, stream>>>(t1, hl2, idxb, n0f);
    k_gconv<<<512, 256, 0, stream>>>(x, idxb, n0f, wb + 75776, gb0, zpb);
    k_econv2<<<640, 256, 0, stream>>>(zpb, wb + 18432, eb2, p2);
    k_tail<<<128, 128, 0, stream>>>(p2, ew3, eb3, cw, cb, out);
}

// Round 5
// 350.665 us; speedup vs baseline: 1.2024x; 1.2024x over previous
//
#include <hip/hip_runtime.h>
#include <hip/hip_bf16.h>
#include <math.h>

typedef unsigned short u16;
typedef __attribute__((ext_vector_type(8))) short short8;
typedef __attribute__((ext_vector_type(4))) float floatx4;

__device__ __forceinline__ float lk(float v){ return v >= 0.f ? v : 0.01f*v; }
__device__ __forceinline__ u16 f2b(float f){
    __hip_bfloat16 h = __float2bfloat16(f);
    return *reinterpret_cast<u16*>(&h);
}
__device__ __forceinline__ int refl(int t, int L){
    return t < 0 ? -t : (t >= L ? 2*L-2-t : t);
}

// ---------------------------------------------------------------------------
// Weight pre-conversion (unchanged layout):
//   [0,4096)        wb1  hconv1: (((s*4+kq)*32)+o)*8+j
//   [4096,18432)    wb2  hconv2: (((s*4+kq)*64)+o)*8+j
//   [18432,75776)   wbe  econv2: (((s*4+kq)*128)+o)*8+j
//   [75776,92160)   gwb  gconv:  (((gi*2+tb)*64)+o)*8+j
// ---------------------------------------------------------------------------
__global__ __launch_bounds__(256) void k_prep(const float* __restrict__ hw1,
        const float* __restrict__ hw2, const float* __restrict__ ew2,
        const float* __restrict__ gw, u16* __restrict__ wb)
{
    int idx = blockIdx.x*256 + threadIdx.x;
    if (idx < 4096){
        int u = idx; int j=u&7; int o=(u>>3)&31; int kq=(u>>8)&3; int s=u>>10;
        int tap = 2*s + (kq>>1); int ic = (kq&1)*8 + j;
        wb[idx] = (tap<7) ? f2b(hw1[(o*16+ic)*7+tap]) : (u16)0;
    } else if (idx < 18432){
        int u = idx - 4096; int j=u&7; int o=(u>>3)&63; int kq=(u>>9)&3; int s=u>>11;
        wb[idx] = f2b(hw2[(o*32 + kq*8 + j)*7 + s]);
    } else if (idx < 75776){
        int u = idx - 18432; int j=u&7; int o=(u>>3)&127; int kq=(u>>10)&3; int s=u>>12;
        int ih = s/7, tap = s-ih*7;
        wb[idx] = f2b(ew2[(o*64 + ih*32 + kq*8 + j)*7 + tap]);
    } else if (idx < 92160){
        int u = idx - 75776; int j=u&7; int o=(u>>3)&63; int tb=(u>>9)&1; int gi=u>>10;
        int tap = tb*8 + j;
        wb[idx] = (tap<15) ? f2b(gw[gi*960 + o*15 + tap]) : (u16)0;
    }
}

// ---------------------------------------------------------------------------
// Hypernet conv1 v5: persistent blocks, 6 tiles of 256 pos each, rolling
// dbuf pipeline; each wave owns a 64-pos quarter and computes BOTH o-halves
// per ds_read (halved LDS read traffic).  grid 1024 = 4 blocks/CU.
// ---------------------------------------------------------------------------
__global__ __launch_bounds__(256,4) void k_hconv1(const float* __restrict__ x,
        const u16* __restrict__ wb1, const float* __restrict__ bias,
        u16* __restrict__ h1)
{
    __shared__ __align__(16) u16 xs[2][264*24];
    __shared__ __align__(16) u16 ob[2][64*32];
    int b = blockIdx.x >> 3, chunk = blockIdx.x & 7;   // 8 chunks x 6 tiles
    int tid = threadIdx.x;
    const float* xb = x + (size_t)b*16*12288;
    int wv = tid >> 6, lane = tid & 63;
    int m = lane & 15, kq = lane >> 4;
    int tq = wv;                                  // wave owns 64-pos quarter

    short8 wfr[4][2];
    #pragma unroll
    for (int s=0;s<4;s++)
        #pragma unroll
        for (int oh=0;oh<2;oh++)
            wfr[s][oh] = *reinterpret_cast<const short8*>(
                            &wb1[(((s*4+kq)*32) + oh*16 + m)*8]);
    float bv[2] = { bias[m], bias[16+m] };

    float rg0[16]; float rgx;
    int exrow = 256 + (tid>>4), exch = tid & 15;

#define LOADTILE(G0) { \
        int t0 = refl((G0) - 3 + tid, 12288); \
        _Pragma("unroll") \
        for (int ic=0;ic<16;ic++) rg0[ic] = xb[(size_t)ic*12288 + t0]; \
        if (tid < 128){ \
            int t1 = refl((G0) - 3 + exrow, 12288); \
            rgx = xb[(size_t)exch*12288 + t1]; \
        } \
        __builtin_amdgcn_sched_barrier(0); }

#define WRITETILE(BUF) { \
        short8 p0, p1; \
        _Pragma("unroll") \
        for (int j=0;j<8;j++){ p0[j] = (short)f2b(rg0[j]); p1[j] = (short)f2b(rg0[8+j]); } \
        *reinterpret_cast<short8*>(&xs[BUF][tid*24])     = p0; \
        *reinterpret_cast<short8*>(&xs[BUF][tid*24 + 8]) = p1; \
        if (tid < 128) xs[BUF][exrow*24 + exch] = f2b(rgx); }

#define COMPUTETILE(BUF) { \
        floatx4 acc[4][2]; \
        _Pragma("unroll") \
        for (int i=0;i<4;i++){ acc[i][0] = (floatx4){0.f,0.f,0.f,0.f}; \
                               acc[i][1] = (floatx4){0.f,0.f,0.f,0.f}; } \
        _Pragma("unroll") \
        for (int sub=0; sub<4; sub++){ \
            int tb = tq*64 + sub*16; \
            _Pragma("unroll") \
            for (int s=0;s<4;s++){ \
                int tap = 2*s + (kq>>1); \
                short8 xfr = *reinterpret_cast<const short8*>( \
                                &xs[BUF][(tb + m + tap)*24 + (kq&1)*8]); \
                acc[sub][0] = __builtin_amdgcn_mfma_f32_16x16x32_bf16(xfr, wfr[s][0], acc[sub][0], 0,0,0); \
                acc[sub][1] = __builtin_amdgcn_mfma_f32_16x16x32_bf16(xfr, wfr[s][1], acc[sub][1], 0,0,0); \
            } \
        } \
        _Pragma("unroll") \
        for (int sub=0; sub<4; sub++){ \
            int p = tq*16 + sub*4 + kq; \
            _Pragma("unroll") \
            for (int oh=0; oh<2; oh++){ \
                float sum = lk(acc[sub][oh][0]+bv[oh]) + lk(acc[sub][oh][1]+bv[oh]) \
                          + lk(acc[sub][oh][2]+bv[oh]) + lk(acc[sub][oh][3]+bv[oh]); \
                ob[BUF][p*32 + oh*16 + m] = f2b(sum*0.25f); \
            } \
        } }

#define STORETILE(BUF, TAU) { \
        short8 v = *reinterpret_cast<const short8*>(&ob[BUF][tid*8]); \
        *reinterpret_cast<short8*>(&h1[((size_t)b*3072 + (TAU)*64)*32 + tid*8]) = v; }

    int tau0 = chunk*6;
    LOADTILE(tau0*256);
    WRITETILE(0);
    __syncthreads();
    LOADTILE((tau0+1)*256);
    #pragma unroll 1
    for (int t=0; t<6; ++t){
        int cur = t & 1;
        COMPUTETILE(cur);
        if (t < 5) WRITETILE(cur^1);
        __syncthreads();
        STORETILE(cur, tau0 + t);
        if (t < 4) LOADTILE((tau0 + t + 2)*256);
    }

#undef LOADTILE
#undef WRITETILE
#undef COMPUTETILE
#undef STORETILE
}

// ---------------------------------------------------------------------------
// Hypernet conv2 v4: h1 bf16 [b][3072][32] -> h2 f32 [b][768 pos][64 ch].
// ---------------------------------------------------------------------------
__global__ __launch_bounds__(256,3) void k_hconv2(const u16* __restrict__ h1,
        const u16* __restrict__ wb2, const float* __restrict__ bias,
        float* __restrict__ h2)
{
    __shared__ __align__(16) u16 xs[2][198*40];
    int b = blockIdx.x >> 3, tile = blockIdx.x & 7;
    int tid = threadIdx.x;
    int wv = tid >> 6, lane = tid & 63;
    int m = lane & 15, kq = lane >> 4;

    float bv[4];
    #pragma unroll
    for (int nt=0;nt<4;nt++) bv[nt] = bias[nt*16 + m];

    short8 rgA[3], rgX;

#define LOADH(HALF) { \
        int gh = tile*384 + (HALF)*192 - 3; \
        _Pragma("unroll") \
        for (int cc=0;cc<3;cc++){ \
            int c = tid + cc*256; \
            int row = c >> 2, q = c & 3; \
            int t = refl(gh + row, 3072); \
            rgA[cc] = *reinterpret_cast<const short8*>(&h1[((size_t)b*3072 + t)*32 + q*8]); \
        } \
        if (tid < 24){ \
            int c = 768 + tid; \
            int row = c >> 2, q = c & 3; \
            int t = refl(gh + row, 3072); \
            rgX = *reinterpret_cast<const short8*>(&h1[((size_t)b*3072 + t)*32 + q*8]); \
        } \
        __builtin_amdgcn_sched_barrier(0); }

#define WRITEH(BUF) { \
        _Pragma("unroll") \
        for (int cc=0;cc<3;cc++){ \
            int c = tid + cc*256; \
            *reinterpret_cast<short8*>(&xs[BUF][(c>>2)*40 + (c&3)*8]) = rgA[cc]; \
        } \
        if (tid < 24){ \
            int c = 768 + tid; \
            *reinterpret_cast<short8*>(&xs[BUF][(c>>2)*40 + (c&3)*8]) = rgX; \
        } }

#define COMPUTEH(BUF, HALF) { \
        floatx4 acc[3][4]; \
        _Pragma("unroll") \
        for (int i=0;i<3;i++) \
            _Pragma("unroll") \
            for (int nt=0;nt<4;nt++) acc[i][nt] = (floatx4){0.f,0.f,0.f,0.f}; \
        _Pragma("unroll") \
        for (int nt2=0; nt2<2; ++nt2){ \
            short8 wfr[7][2]; \
            _Pragma("unroll") \
            for (int s=0;s<7;s++) \
                _Pragma("unroll") \
                for (int c=0;c<2;c++) \
                    wfr[s][c] = *reinterpret_cast<const short8*>( \
                        &wb2[(((s*4+kq)*64) + (nt2*2+c)*16 + m)*8]); \
            _Pragma("unroll") \
            for (int i=0;i<3;i++){ \
                int tb = (wv*3+i)*16; \
                _Pragma("unroll") \
                for (int s=0;s<7;s++){ \
                    short8 xfr = *reinterpret_cast<const short8*>( \
                                    &xs[BUF][(tb + m + s)*40 + kq*8]); \
                    acc[i][nt2*2]   = __builtin_amdgcn_mfma_f32_16x16x32_bf16(xfr, wfr[s][0], acc[i][nt2*2],   0,0,0); \
                    acc[i][nt2*2+1] = __builtin_amdgcn_mfma_f32_16x16x32_bf16(xfr, wfr[s][1], acc[i][nt2*2+1], 0,0,0); \
                } \
            } \
        } \
        _Pragma("unroll") \
        for (int i=0;i<3;i++){ \
            int pooled = (wv*3+i)*4 + kq; \
            _Pragma("unroll") \
            for (int nt=0;nt<4;nt++){ \
                float sum = lk(acc[i][nt][0]+bv[nt]) + lk(acc[i][nt][1]+bv[nt]) \
                          + lk(acc[i][nt][2]+bv[nt]) + lk(acc[i][nt][3]+bv[nt]); \
                h2[((size_t)b*768 + tile*96 + (HALF)*48 + pooled)*64 + nt*16 + m] = sum*0.25f; \
            } \
        } }

    LOADH(0);
    WRITEH(0);
    __syncthreads();
    LOADH(1);
    COMPUTEH(0, 0);
    WRITEH(1);
    __syncthreads();
    COMPUTEH(1, 1);

#undef LOADH
#undef WRITEH
#undef COMPUTEH
}

// ---------------------------------------------------------------------------
// Hypernet conv3 FUSED: h2 f32 [b][768][64] -> latent[128,6144]. (unchanged)
// ---------------------------------------------------------------------------
__global__ __launch_bounds__(256) void k_hconv3(const float* __restrict__ h2,
        const float* __restrict__ w, const float* __restrict__ bias,
        float* __restrict__ latent)
{
    __shared__ float xs[64*201];
    int b = blockIdx.x >> 2, tile = blockIdx.x & 3;
    int g0 = tile*192;
    int tid = threadIdx.x;
    for (int idx = tid; idx < 198*64; idx += 256){
        int jj = idx >> 6, ic = idx & 63;
        int t = refl(g0 + jj - 3, 768);
        xs[ic*201 + jj] = h2[((size_t)b*768 + t)*64 + ic];
    }
    __syncthreads();
    int c = tid >> 5, run = tid & 31;
    int p0 = run*6;
    float acc[6];
    #pragma unroll
    for (int l=0;l<6;l++) acc[l] = 0.f;
    for (int ic=0; ic<64; ic++){
        const float* wp = w + (c*64+ic)*7;
        float wr[7];
        #pragma unroll
        for (int s=0;s<7;s++) wr[s] = wp[s];
        const float* xr = xs + ic*201 + p0;
        float xw[12];
        #pragma unroll
        for (int j=0;j<12;j++) xw[j] = xr[j];
        #pragma unroll
        for (int s=0;s<7;s++)
            #pragma unroll
            for (int l=0;l<6;l++) acc[l] += wr[s]*xw[l+s];
    }
    float bv = bias[c];
    float* op = latent + (size_t)b*6144 + c*768 + g0 + p0;
    #pragma unroll
    for (int l=0;l<6;l++) op[l] = tanhf(acc[l] + bv);
}

// ---------------------------------------------------------------------------
// t1 = leaky(latent @ hl1^T).  (unchanged)
// ---------------------------------------------------------------------------
__global__ __launch_bounds__(256) void k_lin1(const float* __restrict__ latent,
        const float* __restrict__ hl1, float* __restrict__ t1)
{
    __shared__ float ls[6144];
    int b = blockIdx.x / 6, ntile = blockIdx.x % 6;
    int tid = threadIdx.x;
    const float4* lp = reinterpret_cast<const float4*>(latent + (size_t)b*6144);
    float4* lsv = reinterpret_cast<float4*>(ls);
    for (int i = tid; i < 1536; i += 256) lsv[i] = lp[i];
    __syncthreads();
    int wv = tid >> 6, lane = tid & 63;
    #pragma unroll
    for (int nn=0; nn<4; nn++){
        int n = ntile*16 + wv*4 + nn;
        const float4* wp = reinterpret_cast<const float4*>(hl1 + (size_t)n*6144);
        float s = 0.f;
        #pragma unroll
        for (int j=0;j<24;j++){
            float4 q = wp[lane + 64*j];
            float4 l4 = lsv[lane + 64*j];
            s += l4.x*q.x + l4.y*q.y + l4.z*q.z + l4.w*q.w;
        }
        #pragma unroll
        for (int off=32; off; off>>=1) s += __shfl_down(s, off);
        if (lane==0) t1[b*96+n] = lk(s);
    }
}

// ---------------------------------------------------------------------------
// logits = t1 @ hl2^T; top-5; n0 = #(idx<6)   (unchanged)
// ---------------------------------------------------------------------------
__global__ __launch_bounds__(128) void k_topk(const float* __restrict__ t1,
        const float* __restrict__ hl2, int* __restrict__ idxb, float* __restrict__ n0f)
{
    __shared__ float lg[96];
    int b = blockIdx.x, n = threadIdx.x;
    if (n < 96){
        float s = 0.f;
        const float* tp = t1 + b*96;
        const float* wp = hl2 + n*96;
        for (int m=0;m<96;m++) s += tp[m]*wp[m];
        lg[n] = s;
    }
    __syncthreads();
    if (threadIdx.x == 0){
        unsigned long long u0=0ull, u1=0ull;
        float n0 = 0.f;
        for (int k=0;k<5;k++){
            float best = -3.4e38f; int bi = 0;
            for (int m=0;m<96;m++){
                bool used = m<64 ? ((u0>>m)&1ull) : ((u1>>(m-64))&1ull);
                if (!used && lg[m] > best){ best = lg[m]; bi = m; }
            }
            if (bi<64) u0 |= 1ull<<bi; else u1 |= 1ull<<(bi-64);
            idxb[b*5+k] = bi;
            if (bi < 6) n0 += 1.f;
        }
        n0f[b] = n0;
    }
}

// ---------------------------------------------------------------------------
// Grouped idx conv (MFMA), weights from pre-baked gwb. (unchanged)
// ---------------------------------------------------------------------------
__global__ __launch_bounds__(256,3) void k_gconv(const float* __restrict__ x,
        const int* __restrict__ idxb, const float* __restrict__ n0f,
        const u16* __restrict__ gwb, const float* __restrict__ gb0,
        u16* __restrict__ zp)
{
    __shared__ __align__(16) u16 xs[5][8][536];
    __shared__ int nidx[5];
    __shared__ float n0s;
    int b = blockIdx.x >> 2, qc = blockIdx.x & 3;
    int tid = threadIdx.x;
    int p0g = qc*512;

    if (tid < 5) nidx[tid] = idxb[b*5 + tid];
    if (tid == 5) n0s = n0f[b];
    __syncthreads();

    for (int cch = tid; cch < 5*134; cch += 256){
        int k = cch / 134, q = cch - k*134;
        const float* xrow = x + (size_t)b*196608 + (size_t)nidx[k]*2048;
        int base = p0g + q*4;
        u16 vb[4];
        if (base + 3 <= 2047){
            float4 a = *reinterpret_cast<const float4*>(xrow + base);
            vb[0]=f2b(a.x); vb[1]=f2b(a.y); vb[2]=f2b(a.z); vb[3]=f2b(a.w);
        } else {
            #pragma unroll
            for (int jj=0;jj<4;jj++){
                int ii = base+jj; if (ii > 2047) ii = 2047;
                vb[jj] = f2b(xrow[ii]);
            }
        }
        #pragma unroll
        for (int jj=0;jj<4;jj++){
            int gof = q*4 + jj;
            #pragma unroll
            for (int r=0;r<8;r++){
                int i = gof - r;
                if (i >= 0 && i < 528) xs[k][r][i] = vb[jj];
            }
        }
    }

    int wv = tid >> 6, lane = tid & 63;
    int m = lane & 15, kq = lane >> 4;
    int o = wv*16 + m;

    short8 wfr[3];
    #pragma unroll
    for (int c=0;c<3;c++){
        int kk = 2*c + (kq>>1);
        int kkc = kk < 5 ? kk : 4;
        int gi = nidx[kkc] / 6;
        short8 f = *reinterpret_cast<const short8*>(
                        &gwb[(((gi*2 + (kq&1))*64)+o)*8]);
        if (kk >= 5) f = (short8)(short)0;
        wfr[c] = f;
    }
    float bv = n0s * gb0[o];
    __syncthreads();

    int rr = m & 7, ibase = (m & 8) + (kq & 1)*8;
    for (int g8 = 0; g8 < 4; ++g8){
        floatx4 acc[8];
        #pragma unroll
        for (int i=0;i<8;i++) acc[i] = (floatx4){0.f,0.f,0.f,0.f};
        #pragma unroll
        for (int s8=0; s8<8; ++s8){
            int P = (g8*8 + s8)*16;
            #pragma unroll
            for (int c=0;c<3;c++){
                int kk = 2*c + (kq>>1);
                int kkc = kk < 5 ? kk : 4;
                short8 af = *reinterpret_cast<const short8*>(&xs[kkc][rr][P + ibase]);
                acc[s8] = __builtin_amdgcn_mfma_f32_16x16x32_bf16(af, wfr[c], acc[s8], 0,0,0);
            }
        }
        #pragma unroll
        for (int s8=0; s8<8; ++s8){
            int sub = g8*8 + s8;
            int Q = qc*128 + sub*4 + kq;
            if (Q < 508){
                float mx = fmaxf(fmaxf(lk(acc[s8][0]+bv), lk(acc[s8][1]+bv)),
                                 fmaxf(lk(acc[s8][2]+bv), lk(acc[s8][3]+bv)));
                zp[((size_t)b*508 + Q)*64 + o] = f2b(mx);
            }
        }
    }
}

// ---------------------------------------------------------------------------
// Encoder conv2 v3 (MFMA): zp bf16 [b][508][64] -> p2 f32 [b][125][128].
// grid 256 = (b x 2 pos-tiles); weights loaded ONCE per block (each wave
// owns o-tiles {wv, wv+4}: wfr[2][14] = 112 VGPR, (256,1) no spill).
// LDS stride 72 u16 -> 2-way bank conflicts only.
// ---------------------------------------------------------------------------
__global__ __launch_bounds__(256,1) void k_econv2(const u16* __restrict__ zp,
        const u16* __restrict__ wbe, const float* __restrict__ bias,
        float* __restrict__ p2)
{
    __shared__ __align__(16) u16 xs[262*72];
    int b = blockIdx.x >> 1, tile = blockIdx.x & 1;
    int tid = threadIdx.x;
    int r0 = tile*252;                       // conv-position row base
    for (int c = tid; c < 262*8; c += 256){
        int row = c >> 3, q = c & 7;
        int t = r0 + row; if (t > 505) t = 505;
        *reinterpret_cast<short8*>(&xs[row*72 + q*8]) =
            *reinterpret_cast<const short8*>(&zp[((size_t)b*508 + t)*64 + q*8]);
    }
    int wv = tid >> 6, lane = tid & 63;
    int m = lane & 15, kq = lane >> 4;
    int npool = tile ? 62 : 63;

    short8 wfr[2][14];
    #pragma unroll
    for (int h=0;h<2;h++){
        int o = (wv + 4*h)*16 + m;
        #pragma unroll
        for (int s=0;s<14;s++)
            wfr[h][s] = *reinterpret_cast<const short8*>(&wbe[(((s*4+kq)*128)+o)*8]);
    }
    float bv[2] = { bias[wv*16 + m], bias[(wv+4)*16 + m] };
    __syncthreads();

    for (int sub=0; sub<16; sub++){
        floatx4 acc[2];
        acc[0] = (floatx4){0.f,0.f,0.f,0.f};
        acc[1] = (floatx4){0.f,0.f,0.f,0.f};
        #pragma unroll
        for (int s=0;s<14;s++){
            int tap = s%7, ih = s/7;
            short8 xfr = *reinterpret_cast<const short8*>(
                            &xs[(sub*16 + m + tap)*72 + ih*32 + kq*8]);
            acc[0] = __builtin_amdgcn_mfma_f32_16x16x32_bf16(xfr, wfr[0][s], acc[0], 0,0,0);
            acc[1] = __builtin_amdgcn_mfma_f32_16x16x32_bf16(xfr, wfr[1][s], acc[1], 0,0,0);
        }
        int pidx = sub*4 + kq;
        if (pidx < npool){
            #pragma unroll
            for (int h=0;h<2;h++){
                float mx = fmaxf(fmaxf(lk(acc[h][0]+bv[h]), lk(acc[h][1]+bv[h])),
                                 fmaxf(lk(acc[h][2]+bv[h]), lk(acc[h][3]+bv[h])));
                p2[((size_t)b*125 + tile*63 + pidx)*128 + (wv+4*h)*16 + m] = mx;
            }
        }
    }
}

// ---------------------------------------------------------------------------
// Fused tail: sliding sums + feat + classifier + log_softmax. (unchanged)
// ---------------------------------------------------------------------------
__global__ __launch_bounds__(128) void k_tail(const float* __restrict__ p2,
        const float* __restrict__ w, const float* __restrict__ bias,
        const float* __restrict__ cw, const float* __restrict__ cb,
        float* __restrict__ out)
{
    __shared__ float ss[7][128];
    __shared__ float ft[128];
    __shared__ float lgs[5];
    int b = blockIdx.x, tid = threadIdx.x;

    {
        const float* pb = p2 + (size_t)b*125*128 + tid;
        float first6[6], last6[6];
        float c = 0.f;
        #pragma unroll
        for (int t=0;t<6;t++){ float v = pb[(size_t)t*128]; first6[t]=v; c+=v; }
        for (int t=6;t<119;t++) c += pb[(size_t)t*128];
        #pragma unroll
        for (int t=0;t<6;t++) last6[t] = pb[(size_t)(119+t)*128];
        ss[0][tid] = c;
        #pragma unroll
        for (int s=0;s<6;s++){ c = c - first6[s] + last6[s]; ss[s+1][tid] = c; }
    }
    __syncthreads();

    {
        const float* wp = w + (size_t)tid*896;
        float s = 0.f;
        for (int ic=0; ic<128; ic++){
            #pragma unroll
            for (int tp=0; tp<7; tp++)
                s += wp[ic*7+tp]*ss[tp][ic];
        }
        ft[tid] = s*(1.f/119.f) + bias[tid];
    }
    __syncthreads();

    if (tid < 5){
        float lg = cb[tid];
        const float* wp = cw + tid*128;
        for (int o=0;o<128;o++) lg += ft[o]*wp[o];
        lgs[tid] = lg;
    }
    __syncthreads();
    if (tid == 0){
        float mx = -3.4e38f;
        for (int c=0;c<5;c++) mx = fmaxf(mx, lgs[c]);
        float se = 0.f;
        for (int c=0;c<5;c++) se += expf(lgs[c]-mx);
        float lse = mx + logf(se);
        for (int c=0;c<5;c++) out[b*5+c] = lgs[c]-lse;
    }
}

extern "C" void kernel_launch(void* const* d_in, const int* in_sizes, int n_in,
                              void* d_out, int out_size, void* d_ws, size_t ws_size,
                              hipStream_t stream)
{
    const float* x   = (const float*)d_in[0];
    const float* hw1 = (const float*)d_in[2];
    const float* hb1 = (const float*)d_in[3];
    const float* hw2 = (const float*)d_in[4];
    const float* hb2 = (const float*)d_in[5];
    const float* hw3 = (const float*)d_in[6];
    const float* hb3 = (const float*)d_in[7];
    const float* hl1 = (const float*)d_in[8];
    const float* hl2 = (const float*)d_in[9];
    const float* gw  = (const float*)d_in[10];
    const float* gb0 = (const float*)d_in[11];
    const float* ew2 = (const float*)d_in[12];
    const float* eb2 = (const float*)d_in[13];
    const float* ew3 = (const float*)d_in[14];
    const float* eb3 = (const float*)d_in[15];
    const float* cw  = (const float*)d_in[16];
    const float* cb  = (const float*)d_in[17];
    float* out = (float*)d_out;

    float* f       = (float*)d_ws;
    float* latent  = f;
    float* t1      = f + 786432;
    int*   idxb    = (int*)(f + 806432);
    float* n0f     = f + 808432;
    u16*   zpb     = (u16*)(f + 810000);
    u16*   wb      = (u16*)(f + 2900000);
    float* h2      = f + 3932160;
    float* p2      = f + 5000000;
    u16*   h1b     = (u16*)(f + 10223616);

    k_prep<<<360, 256, 0, stream>>>(hw1, hw2, ew2, gw, wb);
    k_hconv1<<<1024, 256, 0, stream>>>(x, wb, hb1, h1b);
    k_hconv2<<<1024, 256, 0, stream>>>(h1b, wb + 4096, hb2, h2);
    k_hconv3<<<512, 256, 0, stream>>>(h2, hw3, hb3, latent);
    k_lin1<<<768, 256, 0, stream>>>(latent, hl1, t1);
    k_topk<<<128, 128, 0, stream>>>(t1, hl2, idxb, n0f);
    k_gconv<<<512, 256, 0, stream>>>(x, idxb, n0f, wb + 75776, gb0, zpb);
    k_econv2<<<256, 256, 0, stream>>>(zpb, wb + 18432, eb2, p2);
    k_tail<<<128, 128, 0, stream>>>(p2, ew3, eb3, cw, cb, out);
}